// Round 2
// baseline (2110.216 us; speedup 1.0000x reference)
//
#include <hip/hip_runtime.h>

#define DEVFN static __device__ __forceinline__

typedef __attribute__((ext_vector_type(8))) short short8;
typedef __attribute__((ext_vector_type(4))) float f32x4;

// ---------- bf16 helpers (raw ushort storage) ----------
DEVFN unsigned short f2bf(float f) {
    union { float f; unsigned u; } a; a.f = f;
    unsigned u = a.u;
    unsigned r = (u + 0x7FFFu + ((u >> 16) & 1u)) >> 16;   // RNE
    return (unsigned short)r;
}
DEVFN float bf2f(unsigned short b) {
    union { unsigned u; float f; } a; a.u = ((unsigned)b) << 16;
    return a.f;
}
DEVFN float2 bfpair(unsigned v) {
    float2 r;
    union { unsigned u; float f; } a;
    a.u = (v & 0xFFFFu) << 16; r.x = a.f;
    a.u = v & 0xFFFF0000u;     r.y = a.f;
    return r;
}

// ---------- async global->LDS (16B per lane, wave-uniform LDS base) ----------
DEVFN void gload16(const void* g, void* lds) {
    __builtin_amdgcn_global_load_lds(
        (const __attribute__((address_space(1))) unsigned int*)g,
        (__attribute__((address_space(3))) unsigned int*)lds, 16, 0, 0);
}

#define SB0() __builtin_amdgcn_sched_barrier(0)
#define PH_BARRIER() do { SB0(); __builtin_amdgcn_s_barrier(); SB0(); } while (0)
#define VMCNT6() do { asm volatile("s_waitcnt vmcnt(6)" ::: "memory"); SB0(); } while (0)
#define VMCNT0() do { asm volatile("s_waitcnt vmcnt(0)" ::: "memory"); SB0(); } while (0)

// ---------- prep: xs = [x | rwkv] cast bf16 ----------
__global__ __launch_bounds__(256) void pack_xs_kernel(
        const float* __restrict__ x, const float* __restrict__ r,
        unsigned short* __restrict__ xs) {
    int i = blockIdx.x * 256 + threadIdx.x;
    int n  = i >> 10;
    int cw = i & 1023;
    const float* src = (cw < 512) ? (x + (size_t)n * 2048 + cw * 4)
                                  : (r + (size_t)n * 2048 + (cw - 512) * 4);
    float4 v = *(const float4*)src;
    ushort4 o;
    o.x = f2bf(v.x); o.y = f2bf(v.y); o.z = f2bf(v.z); o.w = f2bf(v.w);
    *(ushort4*)(xs + (size_t)n * 4096 + cw * 4) = o;
}

// ---------- prep: transpose + cast fp32[R][Cc] -> bf16[Cc][R] ----------
__global__ __launch_bounds__(256) void transpose_cast_kernel(
        const float* __restrict__ in, unsigned short* __restrict__ out,
        int R, int Cc) {
    __shared__ float tile[32][33];
    int tx = threadIdx.x & 31, ty = threadIdx.x >> 5;
    int tr = blockIdx.y * 32, tc = blockIdx.x * 32;
#pragma unroll
    for (int i = 0; i < 4; i++) {
        int rr = ty + i * 8;
        tile[rr][tx] = in[(size_t)(tr + rr) * Cc + tc + tx];
    }
    __syncthreads();
#pragma unroll
    for (int i = 0; i < 4; i++) {
        int rr = ty + i * 8;
        out[(size_t)(tc + rr) * R + tr + tx] = f2bf(tile[tx][rr]);
    }
}

// ============================================================================
// 256x256 8-phase GEMM: C[M,N] = A[M,K](bf16,row) * Bt[N,K](bf16,row)^T
// BK=64, 8 waves (2Mx4N), 128 KiB LDS (2 dbuf x {A,B} x 2 halves x 16KB),
// st_16x32 XOR swizzle (pre-swizzled global src + swizzled ds_read),
// counted vmcnt(6), setprio around MFMA clusters, bijective XCD swizzle.
// EPI: 0 = store bf16; 1 = sigmoid(acc + aux_f32[col]) bf16;
//      2 = loss: sum((acc - aux_f32[row*ldc+col])^2) -> atomicAdd;
//      3 = store fp32 acc * bf2f(aux_bf16[row*ldc+col])
// ============================================================================
template <int EPI>
__global__ __launch_bounds__(512, 2) void gemm256(
        const unsigned short* __restrict__ A, int lda,
        const unsigned short* __restrict__ Bt, int ldb,
        void* __restrict__ Cptr, int ldc, int K, int Ntiles,
        const float* __restrict__ aux_f32,
        const unsigned short* __restrict__ aux_bf16,
        float* __restrict__ loss_accum) {
    extern __shared__ char smem[];   // 131072 B
    const int tid  = threadIdx.x;
    const int wid  = tid >> 6, lane = tid & 63;
    const int wm   = wid >> 2, wn = wid & 3;
    const int l15  = lane & 15;
    const int lhi  = (lane >> 4) * 16;         // byte offset of k-group
    const int nkt  = K >> 6;                   // K-tiles of 64

    // bijective XCD swizzle (m204)
    const int nwg = gridDim.x;
    {
    }
    int wg = blockIdx.x;
    int q = nwg >> 3, r = nwg & 7;
    int xcd = wg & 7, idx = wg >> 3;
    int swz = (xcd < r ? xcd * (q + 1) : r * (q + 1) + (xcd - r) * q) + idx;
    const int brow = (swz / Ntiles) << 8;
    const int bcol = (swz % Ntiles) << 8;

    // per-thread stage addressing: chunk c = wid*2+j covers LDS [c*1024, +1024)
    // linear dest; SOURCE pre-swizzled: lin -> phys = lin ^ ((lin>>9 &1)<<5)
    const int lin0 = (wid * 2 + 0) * 1024 + lane * 16;
    const int lin1 = (wid * 2 + 1) * 1024 + lane * 16;
    const int ph0 = lin0 ^ (((lin0 >> 9) & 1) << 5);
    const int ph1 = lin1 ^ (((lin1 >> 9) & 1) << 5);
    const int srow0 = ph0 >> 7, scol0 = (ph0 & 127) >> 1;
    const int srow1 = ph1 >> 7, scol1 = (ph1 & 127) >> 1;
    const int dst0 = (wid * 2 + 0) * 1024;
    const int dst1 = (wid * 2 + 1) * 1024;

    // stage half-tile: tile t, mat 0=A 1=B, half h (128 rows x 64 k-cols)
#define STAGE(t, mat, h) do { \
        char* base_ = smem + (((t) & 1) * 65536) + ((mat) * 32768) + ((h) * 16384); \
        const unsigned short* G_ = (mat) ? Bt : A; \
        const int ld_ = (mat) ? ldb : lda; \
        const int rb_ = ((mat) ? bcol : brow) + (h) * 128; \
        gload16(G_ + (size_t)(rb_ + srow0) * ld_ + (t) * 64 + scol0, base_ + dst0); \
        gload16(G_ + (size_t)(rb_ + srow1) * ld_ + (t) * 64 + scol1, base_ + dst1); \
    } while (0)
#define STAGE_G(t, mat, h) do { if ((t) < nkt) STAGE(t, mat, h); } while (0)

    // swizzled fragment reads
#define LDA_FRAG(dst, buf, m, kk) do { \
        int lin_ = ((m) * 16 + l15) * 128 + (kk) * 64 + lhi; \
        int ph_  = lin_ ^ (((lin_ >> 9) & 1) << 5); \
        dst = *(const short8*)(smem + (buf) * 65536 + wm * 16384 + ph_); \
    } while (0)
#define LDB_FRAG(dst, buf, n, kk) do { \
        int lin_ = ((wn & 1) * 64 + (n) * 16 + l15) * 128 + (kk) * 64 + lhi; \
        int ph_  = lin_ ^ (((lin_ >> 9) & 1) << 5); \
        dst = *(const short8*)(smem + (buf) * 65536 + 32768 + (wn >> 1) * 16384 + ph_); \
    } while (0)

    f32x4 acc[8][4] = {};
    short8 afr[8][2], bfr[4][2];

#define MFMA_Q(mq) do { \
        __builtin_amdgcn_s_setprio(1); \
        _Pragma("unroll") \
        for (int n_ = 0; n_ < 4; ++n_) { \
            acc[2*(mq)][n_]   = __builtin_amdgcn_mfma_f32_16x16x32_bf16(afr[2*(mq)][0],   bfr[n_][0], acc[2*(mq)][n_],   0,0,0); \
            acc[2*(mq)][n_]   = __builtin_amdgcn_mfma_f32_16x16x32_bf16(afr[2*(mq)][1],   bfr[n_][1], acc[2*(mq)][n_],   0,0,0); \
            acc[2*(mq)+1][n_] = __builtin_amdgcn_mfma_f32_16x16x32_bf16(afr[2*(mq)+1][0], bfr[n_][0], acc[2*(mq)+1][n_], 0,0,0); \
            acc[2*(mq)+1][n_] = __builtin_amdgcn_mfma_f32_16x16x32_bf16(afr[2*(mq)+1][1], bfr[n_][1], acc[2*(mq)+1][n_], 0,0,0); \
        } \
        __builtin_amdgcn_s_setprio(0); \
    } while (0)

    // ---- prologue: stage T0 fully + T1.{B0,B1,A0}; drain so T0 landed ----
    STAGE(0, 1, 0); STAGE(0, 1, 1); STAGE(0, 0, 0); STAGE(0, 0, 1);
    STAGE_G(1, 1, 0); STAGE_G(1, 1, 1); STAGE_G(1, 0, 0);
    VMCNT6();
    PH_BARRIER();

    const int niter = nkt >> 1;
    for (int it = 0; it < niter; ++it) {
        const int t0 = it * 2, t1 = t0 + 1;
        const bool lastIt = (it == niter - 1);

        // ================= group A: tile t0 in buf 0 =================
        // phase 1: read B (8) + A m0-3 (8); stage T(t1).A1
#pragma unroll
        for (int n_ = 0; n_ < 4; ++n_) {
            LDB_FRAG(bfr[n_][0], 0, n_, 0); LDB_FRAG(bfr[n_][1], 0, n_, 1);
        }
#pragma unroll
        for (int m_ = 0; m_ < 4; ++m_) {
            LDA_FRAG(afr[m_][0], 0, m_, 0); LDA_FRAG(afr[m_][1], 0, m_, 1);
        }
        STAGE_G(t1, 0, 1);
        PH_BARRIER();
        MFMA_Q(0);
        PH_BARRIER();
        // phase 2: read A m4-7; stage T(t0+2).B0
#pragma unroll
        for (int m_ = 4; m_ < 8; ++m_) {
            LDA_FRAG(afr[m_][0], 0, m_, 0); LDA_FRAG(afr[m_][1], 0, m_, 1);
        }
        STAGE_G(t0 + 2, 1, 0);
        PH_BARRIER();
        MFMA_Q(1);
        PH_BARRIER();
        // phase 3: stage T(t0+2).B1
        STAGE_G(t0 + 2, 1, 1);
        PH_BARRIER();
        MFMA_Q(2);
        PH_BARRIER();
        // phase 4: stage T(t0+2).A0; checkpoint
        STAGE_G(t0 + 2, 0, 0);
        PH_BARRIER();
        MFMA_Q(3);
        if (lastIt) { VMCNT0(); } else { VMCNT6(); }
        PH_BARRIER();

        // ================= group B: tile t1 in buf 1 =================
        // phase 5: read B + A m0-3 from buf1; stage T(t0+2).A1
#pragma unroll
        for (int n_ = 0; n_ < 4; ++n_) {
            LDB_FRAG(bfr[n_][0], 1, n_, 0); LDB_FRAG(bfr[n_][1], 1, n_, 1);
        }
#pragma unroll
        for (int m_ = 0; m_ < 4; ++m_) {
            LDA_FRAG(afr[m_][0], 1, m_, 0); LDA_FRAG(afr[m_][1], 1, m_, 1);
        }
        STAGE_G(t0 + 2, 0, 1);
        PH_BARRIER();
        MFMA_Q(0);
        PH_BARRIER();
        // phase 6: read A m4-7; stage T(t1+2).B0
#pragma unroll
        for (int m_ = 4; m_ < 8; ++m_) {
            LDA_FRAG(afr[m_][0], 1, m_, 0); LDA_FRAG(afr[m_][1], 1, m_, 1);
        }
        STAGE_G(t1 + 2, 1, 0);
        PH_BARRIER();
        MFMA_Q(1);
        PH_BARRIER();
        // phase 7: stage T(t1+2).B1
        STAGE_G(t1 + 2, 1, 1);
        PH_BARRIER();
        MFMA_Q(2);
        PH_BARRIER();
        // phase 8: stage T(t1+2).A0; checkpoint
        STAGE_G(t1 + 2, 0, 0);
        PH_BARRIER();
        MFMA_Q(3);
        if (lastIt) { VMCNT0(); } else { VMCNT6(); }
        PH_BARRIER();
    }

    // ---- epilogue: C/D layout col = lane&15, row = (lane>>4)*4 + reg ----
    const int rl = (lane >> 4) * 4;
    const int cl = lane & 15;
    const int row0 = brow + wm * 128;
    const int col0 = bcol + wn * 64;

    if constexpr (EPI == 2) {
        float lsum = 0.f;
#pragma unroll
        for (int m = 0; m < 8; m++)
#pragma unroll
            for (int n = 0; n < 4; n++)
#pragma unroll
                for (int rg = 0; rg < 4; rg++) {
                    int gr = row0 + m * 16 + rl + rg;
                    int gc = col0 + n * 16 + cl;
                    float d = acc[m][n][rg] - aux_f32[(size_t)gr * ldc + gc];
                    lsum += d * d;
                }
#pragma unroll
        for (int msk = 1; msk < 64; msk <<= 1)
            lsum += __shfl_xor(lsum, msk, 64);
        if (lane == 0) atomicAdd(loss_accum, lsum);
        return;
    }

#pragma unroll
    for (int m = 0; m < 8; m++)
#pragma unroll
        for (int n = 0; n < 4; n++)
#pragma unroll
            for (int rg = 0; rg < 4; rg++) {
                int gr = row0 + m * 16 + rl + rg;
                int gc = col0 + n * 16 + cl;
                size_t idxo = (size_t)gr * ldc + gc;
                if constexpr (EPI == 0) {
                    ((unsigned short*)Cptr)[idxo] = f2bf(acc[m][n][rg]);
                } else if constexpr (EPI == 1) {
                    float t = acc[m][n][rg] + aux_f32[gc];
                    ((unsigned short*)Cptr)[idxo] = f2bf(1.f / (1.f + expf(-t)));
                } else {  // EPI == 3
                    float gv = bf2f(aux_bf16[idxo]);
                    ((float*)Cptr)[idxo] = acc[m][n][rg] * gv;
                }
            }
#undef STAGE
#undef STAGE_G
#undef LDA_FRAG
#undef LDB_FRAG
#undef MFMA_Q
}

// ---------- pmean[n][c] = mean_p prefix[n][p*2048 + c] ----------
__global__ __launch_bounds__(256) void pmean_kernel(
        const unsigned short* __restrict__ prefix, unsigned short* __restrict__ pm) {
    int i  = blockIdx.x * 256 + threadIdx.x;
    int n  = i >> 8;
    int c8 = (i & 255) * 8;
    float acc[8] = {0, 0, 0, 0, 0, 0, 0, 0};
#pragma unroll
    for (int p = 0; p < 8; p++) {
        const unsigned short* src = prefix + (size_t)n * 16384 + p * 2048 + c8;
        uint4 raw = *(const uint4*)src;
        unsigned w[4] = {raw.x, raw.y, raw.z, raw.w};
#pragma unroll
        for (int j = 0; j < 4; j++) {
            float2 fp = bfpair(w[j]);
            acc[2 * j] += fp.x; acc[2 * j + 1] += fp.y;
        }
    }
    uint4 o;
    unsigned* ow = (unsigned*)&o;
#pragma unroll
    for (int j = 0; j < 4; j++)
        ow[j] = (unsigned)f2bf(acc[2 * j] * 0.125f) |
                ((unsigned)f2bf(acc[2 * j + 1] * 0.125f) << 16);
    *(uint4*)(pm + (size_t)n * 2048 + c8) = o;
}

// ---------- attention: one wave per (n,h), P=8 keys, D=128 ----------
__global__ __launch_bounds__(256) void attn_kernel(
        const unsigned short* __restrict__ q, const unsigned short* __restrict__ k,
        const unsigned short* __restrict__ v, unsigned short* __restrict__ o) {
    int gw   = (blockIdx.x * 256 + threadIdx.x) >> 6;
    int lane = threadIdx.x & 63;
    int n = gw >> 4, h = gw & 15;
    size_t qoff = (size_t)n * 2048 + h * 128 + lane * 2;
    float2 qv = bfpair(*(const unsigned*)(q + qoff));
    float s[8];
#pragma unroll
    for (int p = 0; p < 8; p++) {
        size_t koff = (size_t)(n * 8 + p) * 2048 + h * 128 + lane * 2;
        float2 kv = bfpair(*(const unsigned*)(k + koff));
        float d = qv.x * kv.x + qv.y * kv.y;
#pragma unroll
        for (int msk = 1; msk < 64; msk <<= 1) d += __shfl_xor(d, msk, 64);
        s[p] = d * 0.08838834764831845f;
    }
    float mx = s[0];
#pragma unroll
    for (int p = 1; p < 8; p++) mx = fmaxf(mx, s[p]);
    float e[8], den = 0.f;
#pragma unroll
    for (int p = 0; p < 8; p++) { e[p] = expf(s[p] - mx); den += e[p]; }
    float inv = 1.f / den;
    float o0 = 0.f, o1 = 0.f;
#pragma unroll
    for (int p = 0; p < 8; p++) {
        size_t voff = (size_t)(n * 8 + p) * 2048 + h * 128 + lane * 2;
        float2 vv = bfpair(*(const unsigned*)(v + voff));
        float a = e[p] * inv;
        o0 += a * vv.x; o1 += a * vv.y;
    }
    *(unsigned*)(o + qoff) = (unsigned)f2bf(o0) | ((unsigned)f2bf(o1) << 16);
}

__global__ __launch_bounds__(64) void finalize_loss_kernel(
        const float* __restrict__ accum, float* __restrict__ dst) {
    if (threadIdx.x == 0) dst[0] = accum[0] * (1.0f / (4096.0f * 2048.0f));
}

// ---------- launch ----------
extern "C" void kernel_launch(void* const* d_in, const int* in_sizes, int n_in,
                              void* d_out, int out_size, void* d_ws, size_t ws_size,
                              hipStream_t stream) {
    const float* x    = (const float*)d_in[0];
    const float* rwkv = (const float*)d_in[1];
    const float* Wq   = (const float*)d_in[2];
    const float* Wk   = (const float*)d_in[3];
    const float* Wv   = (const float*)d_in[4];
    const float* Wo   = (const float*)d_in[5];
    const float* Wg   = (const float*)d_in[6];
    const float* bg   = (const float*)d_in[7];
    const float* Wb   = (const float*)d_in[8];
    const float* Wr   = (const float*)d_in[9];
    float* out = (float*)d_out;
    char*  ws  = (char*)d_ws;

    unsigned short* xs     = (unsigned short*)(ws + 0ull);
    unsigned short* wbT    = (unsigned short*)(ws + 33554432ull);
    unsigned short* wqT    = (unsigned short*)(ws + 167772160ull);
    unsigned short* wkT    = (unsigned short*)(ws + 176160768ull);
    unsigned short* wvT    = (unsigned short*)(ws + 184549376ull);
    unsigned short* wgT    = (unsigned short*)(ws + 192937984ull);
    unsigned short* wrT    = (unsigned short*)(ws + 201326592ull);
    unsigned short* woT    = (unsigned short*)(ws + 209715200ull);
    unsigned short* prefix = (unsigned short*)(ws + 218103808ull);
    unsigned short* vbuf   = (unsigned short*)(ws + 352321536ull);
    unsigned short* qbuf   = (unsigned short*)(ws + 486539264ull);
    unsigned short* gbuf   = (unsigned short*)(ws + 503316480ull);
    unsigned short* pmean  = (unsigned short*)(ws + 520093696ull);
    unsigned short* attno  = (unsigned short*)(ws + 536870912ull);
    float*          lossA  = (float*)(ws + 553648128ull);
    unsigned short* kbuf   = wbT;   // WbT dead after bridge GEMM

    const int SMEM = 131072;
    hipFuncSetAttribute(reinterpret_cast<const void*>(gemm256<0>),
                        hipFuncAttributeMaxDynamicSharedMemorySize, SMEM);
    hipFuncSetAttribute(reinterpret_cast<const void*>(gemm256<1>),
                        hipFuncAttributeMaxDynamicSharedMemorySize, SMEM);
    hipFuncSetAttribute(reinterpret_cast<const void*>(gemm256<2>),
                        hipFuncAttributeMaxDynamicSharedMemorySize, SMEM);
    hipFuncSetAttribute(reinterpret_cast<const void*>(gemm256<3>),
                        hipFuncAttributeMaxDynamicSharedMemorySize, SMEM);

    hipMemsetAsync(lossA, 0, 16, stream);

    pack_xs_kernel<<<16384, 256, 0, stream>>>(x, rwkv, xs);
    transpose_cast_kernel<<<dim3(512, 128), 256, 0, stream>>>(Wb, wbT, 4096, 16384);
    transpose_cast_kernel<<<dim3(64, 64),  256, 0, stream>>>(Wq, wqT, 2048, 2048);
    transpose_cast_kernel<<<dim3(64, 64),  256, 0, stream>>>(Wk, wkT, 2048, 2048);
    transpose_cast_kernel<<<dim3(64, 64),  256, 0, stream>>>(Wv, wvT, 2048, 2048);
    transpose_cast_kernel<<<dim3(64, 64),  256, 0, stream>>>(Wg, wgT, 2048, 2048);
    transpose_cast_kernel<<<dim3(64, 64),  256, 0, stream>>>(Wr, wrT, 2048, 2048);
    transpose_cast_kernel<<<dim3(64, 64),  256, 0, stream>>>(Wo, woT, 2048, 2048);

    // prefix = xs @ Wb          M=4096 N=16384 K=4096 -> 16x64 tiles
    gemm256<0><<<dim3(1024), 512, SMEM, stream>>>(xs, 4096, wbT, 4096,
        prefix, 16384, 4096, 64, nullptr, nullptr, nullptr);
    // k = prefix @ Wk           M=32768 N=2048 K=2048 -> 128x8 tiles
    gemm256<0><<<dim3(1024), 512, SMEM, stream>>>(prefix, 2048, wkT, 2048,
        kbuf, 2048, 2048, 8, nullptr, nullptr, nullptr);
    // v = prefix @ Wv
    gemm256<0><<<dim3(1024), 512, SMEM, stream>>>(prefix, 2048, wvT, 2048,
        vbuf, 2048, 2048, 8, nullptr, nullptr, nullptr);
    // pmean = mean_p(prefix)
    pmean_kernel<<<4096, 256, 0, stream>>>(prefix, pmean);
    // q = x @ Wq   (x = first 2048 cols of xs, lda=4096)  16x8 tiles
    gemm256<0><<<dim3(128), 512, SMEM, stream>>>(xs, 4096, wqT, 2048,
        qbuf, 2048, 2048, 8, nullptr, nullptr, nullptr);
    // g = sigmoid(x @ Wg + bg)
    gemm256<1><<<dim3(128), 512, SMEM, stream>>>(xs, 4096, wgT, 2048,
        gbuf, 2048, 2048, 8, bg, nullptr, nullptr);
    // recon loss: sum((pmean @ Wr - x)^2)
    gemm256<2><<<dim3(128), 512, SMEM, stream>>>(pmean, 2048, wrT, 2048,
        nullptr, 2048, 2048, 8, x, nullptr, lossA);
    // attention
    attn_kernel<<<16384, 256, 0, stream>>>(qbuf, kbuf, vbuf, attno);
    // out = (attno @ Wo) * g    -> fp32 d_out
    gemm256<3><<<dim3(128), 512, SMEM, stream>>>(attno, 2048, woT, 2048,
        out, 2048, 2048, 8, nullptr, gbuf, nullptr);

    finalize_loss_kernel<<<1, 64, 0, stream>>>(lossA, out + 8388608);
}

// Round 5
// 1427.754 us; speedup vs baseline: 1.4780x; 1.4780x over previous
//
#include <hip/hip_runtime.h>

#define DEVFN static __device__ __forceinline__

typedef __attribute__((ext_vector_type(8))) short short8;
typedef __attribute__((ext_vector_type(4))) float f32x4;

// ---------- bf16 helpers (raw ushort storage) ----------
DEVFN unsigned short f2bf(float f) {
    union { float f; unsigned u; } a; a.f = f;
    unsigned u = a.u;
    unsigned r = (u + 0x7FFFu + ((u >> 16) & 1u)) >> 16;   // RNE
    return (unsigned short)r;
}
DEVFN float bf2f(unsigned short b) {
    union { unsigned u; float f; } a; a.u = ((unsigned)b) << 16;
    return a.f;
}
DEVFN float2 bfpair(unsigned v) {
    float2 r;
    union { unsigned u; float f; } a;
    a.u = (v & 0xFFFFu) << 16; r.x = a.f;
    a.u = v & 0xFFFF0000u;     r.y = a.f;
    return r;
}

// ---------- async global->LDS (16B per lane, wave-uniform LDS base) ----------
DEVFN void gload16(const void* g, void* lds) {
    __builtin_amdgcn_global_load_lds(
        (const __attribute__((address_space(1))) unsigned int*)g,
        (__attribute__((address_space(3))) unsigned int*)lds, 16, 0, 0);
}

#define SB0() __builtin_amdgcn_sched_barrier(0)
#define PH_BARRIER() do { SB0(); __builtin_amdgcn_s_barrier(); SB0(); } while (0)
#define VMCNT4() do { asm volatile("s_waitcnt vmcnt(4)" ::: "memory"); SB0(); } while (0)
#define VMCNT0() do { asm volatile("s_waitcnt vmcnt(0)" ::: "memory"); SB0(); } while (0)

// ---------- prep: xs = [x | rwkv] cast bf16 ----------
__global__ __launch_bounds__(256) void pack_xs_kernel(
        const float* __restrict__ x, const float* __restrict__ r,
        unsigned short* __restrict__ xs) {
    int i = blockIdx.x * 256 + threadIdx.x;
    int n  = i >> 10;
    int cw = i & 1023;
    const float* src = (cw < 512) ? (x + (size_t)n * 2048 + cw * 4)
                                  : (r + (size_t)n * 2048 + (cw - 512) * 4);
    float4 v = *(const float4*)src;
    ushort4 o;
    o.x = f2bf(v.x); o.y = f2bf(v.y); o.z = f2bf(v.z); o.w = f2bf(v.w);
    *(ushort4*)(xs + (size_t)n * 4096 + cw * 4) = o;
}

// ---------- prep: transpose + cast fp32[R][Cc] -> bf16[Cc][R] ----------
__global__ __launch_bounds__(256) void transpose_cast_kernel(
        const float* __restrict__ in, unsigned short* __restrict__ out,
        int R, int Cc) {
    __shared__ float tile[32][33];
    int tx = threadIdx.x & 31, ty = threadIdx.x >> 5;
    int tr = blockIdx.y * 32, tc = blockIdx.x * 32;
#pragma unroll
    for (int i = 0; i < 4; i++) {
        int rr = ty + i * 8;
        tile[rr][tx] = in[(size_t)(tr + rr) * Cc + tc + tx];
    }
    __syncthreads();
#pragma unroll
    for (int i = 0; i < 4; i++) {
        int rr = ty + i * 8;
        out[(size_t)(tc + rr) * R + tr + tx] = f2bf(tile[tx][rr]);
    }
}

// ============================================================================
// 256x256 8-phase GEMM: C[M,N] = A[M,K](bf16,row) * Bt[N,K](bf16,row)^T
// BK=64, 8 waves (2Mx4N), 128 KiB LDS, 8-slot XOR swizzle
// (phys = lin ^ ((lin>>7 & 7)<<4); pre-swizzled global src + swizzled ds_read).
// Race-free stage schedule (stage into region R only after R's reads ran):
//   ph1: T(t1).A0+A1 -> buf1    ph5: T(t0+2).A0+A1 -> buf0
//   ph2: T(t0+2).B0  -> buf0    ph6: T(t1+2).B0    -> buf1
//   ph3: T(t0+2).B1  -> buf0    ph7: T(t1+2).B1    -> buf1
//   ph4: ckpt vmcnt(4)          ph8: ckpt vmcnt(4)
// LAST ITERATION: ph2/3/6/7 stages are skipped, so vmcnt(4) would leave
// T(t1).A itself outstanding -> must drain with vmcnt(0) (the R3/R4 bug).
// EPI: 0 = store bf16; 1 = sigmoid(acc + aux_f32[col]) bf16;
//      2 = loss: sum((acc - aux_f32[row*ldc+col])^2) -> atomicAdd;
//      3 = store fp32 acc * bf2f(aux_bf16[row*ldc+col])
// ============================================================================
template <int EPI>
__global__ __launch_bounds__(512, 2) void gemm256(
        const unsigned short* __restrict__ A, int lda,
        const unsigned short* __restrict__ Bt, int ldb,
        void* __restrict__ Cptr, int ldc, int K, int Ntiles,
        const float* __restrict__ aux_f32,
        const unsigned short* __restrict__ aux_bf16,
        float* __restrict__ loss_accum) {
    extern __shared__ char smem[];   // 131072 B
    const int tid  = threadIdx.x;
    const int wid  = tid >> 6, lane = tid & 63;
    const int wm   = wid >> 2, wn = wid & 3;
    const int l15  = lane & 15;
    const int lhi  = (lane >> 4) * 16;         // byte offset of k-group
    const int nkt  = K >> 6;                   // K-tiles of 64

    // bijective XCD swizzle (m204)
    const int nwg = gridDim.x;
    int wg = blockIdx.x;
    int q = nwg >> 3, r = nwg & 7;
    int xcd = wg & 7, idx = wg >> 3;
    int swz = (xcd < r ? xcd * (q + 1) : r * (q + 1) + (xcd - r) * q) + idx;
    const int brow = (swz / Ntiles) << 8;
    const int bcol = (swz % Ntiles) << 8;

    // per-thread stage addressing: chunk c = wid*2+j covers LDS [c*1024, +1024)
    // linear dest; SOURCE pre-swizzled: phys = lin ^ ((lin>>7 & 7)<<4)
    const int lin0 = (wid * 2 + 0) * 1024 + lane * 16;
    const int lin1 = (wid * 2 + 1) * 1024 + lane * 16;
    const int ph0 = lin0 ^ (((lin0 >> 7) & 7) << 4);
    const int ph1v = lin1 ^ (((lin1 >> 7) & 7) << 4);
    const int srow0 = ph0 >> 7, scol0 = (ph0 & 127) >> 1;
    const int srow1 = ph1v >> 7, scol1 = (ph1v & 127) >> 1;
    const int dst0 = (wid * 2 + 0) * 1024;
    const int dst1 = (wid * 2 + 1) * 1024;

    // stage half-tile: tile t, mat 0=A 1=B, half h (128 rows x 64 k-cols)
#define STAGE(t, mat, h) do { \
        char* base_ = smem + (((t) & 1) * 65536) + ((mat) * 32768) + ((h) * 16384); \
        const unsigned short* G_ = (mat) ? Bt : A; \
        const int ld_ = (mat) ? ldb : lda; \
        const int rb_ = ((mat) ? bcol : brow) + (h) * 128; \
        gload16(G_ + (size_t)(rb_ + srow0) * ld_ + (t) * 64 + scol0, base_ + dst0); \
        gload16(G_ + (size_t)(rb_ + srow1) * ld_ + (t) * 64 + scol1, base_ + dst1); \
    } while (0)
#define STAGE_G(t, mat, h) do { if ((t) < nkt) STAGE(t, mat, h); } while (0)

    // swizzled fragment reads
#define LDA_FRAG(dst, buf, m, kk) do { \
        int lin_ = ((m) * 16 + l15) * 128 + (kk) * 64 + lhi; \
        int ph_  = lin_ ^ (((lin_ >> 7) & 7) << 4); \
        dst = *(const short8*)(smem + (buf) * 65536 + wm * 16384 + ph_); \
    } while (0)
#define LDB_FRAG(dst, buf, n, kk) do { \
        int lin_ = ((wn & 1) * 64 + (n) * 16 + l15) * 128 + (kk) * 64 + lhi; \
        int ph_  = lin_ ^ (((lin_ >> 7) & 7) << 4); \
        dst = *(const short8*)(smem + (buf) * 65536 + 32768 + (wn >> 1) * 16384 + ph_); \
    } while (0)

    f32x4 acc[8][4] = {};
    short8 afr[8][2], bfr[4][2];

#define MFMA_Q(mq) do { \
        __builtin_amdgcn_s_setprio(1); \
        _Pragma("unroll") \
        for (int n_ = 0; n_ < 4; ++n_) { \
            acc[2*(mq)][n_]   = __builtin_amdgcn_mfma_f32_16x16x32_bf16(afr[2*(mq)][0],   bfr[n_][0], acc[2*(mq)][n_],   0,0,0); \
            acc[2*(mq)][n_]   = __builtin_amdgcn_mfma_f32_16x16x32_bf16(afr[2*(mq)][1],   bfr[n_][1], acc[2*(mq)][n_],   0,0,0); \
            acc[2*(mq)+1][n_] = __builtin_amdgcn_mfma_f32_16x16x32_bf16(afr[2*(mq)+1][0], bfr[n_][0], acc[2*(mq)+1][n_], 0,0,0); \
            acc[2*(mq)+1][n_] = __builtin_amdgcn_mfma_f32_16x16x32_bf16(afr[2*(mq)+1][1], bfr[n_][1], acc[2*(mq)+1][n_], 0,0,0); \
        } \
        __builtin_amdgcn_s_setprio(0); \
    } while (0)

// read fragments for quadrant q from buffer b (phase q=0 also reads all B)
#define READ_Q0(b) do { \
        _Pragma("unroll") \
        for (int n_ = 0; n_ < 4; ++n_) { LDB_FRAG(bfr[n_][0], b, n_, 0); LDB_FRAG(bfr[n_][1], b, n_, 1); } \
        LDA_FRAG(afr[0][0], b, 0, 0); LDA_FRAG(afr[0][1], b, 0, 1); \
        LDA_FRAG(afr[1][0], b, 1, 0); LDA_FRAG(afr[1][1], b, 1, 1); \
    } while (0)
#define READ_QA(b, mq) do { \
        LDA_FRAG(afr[2*(mq)][0],   b, 2*(mq),   0); LDA_FRAG(afr[2*(mq)][1],   b, 2*(mq),   1); \
        LDA_FRAG(afr[2*(mq)+1][0], b, 2*(mq)+1, 0); LDA_FRAG(afr[2*(mq)+1][1], b, 2*(mq)+1, 1); \
    } while (0)

    // ---- prologue: T0 full + T1.B0,B1 (T1.A staged in iter-0 ph1) ----
    STAGE(0, 1, 0); STAGE(0, 1, 1); STAGE(0, 0, 0); STAGE(0, 0, 1);
    STAGE_G(1, 1, 0); STAGE_G(1, 1, 1);
    VMCNT4();        // T0 landed (newest 4 = T1.B)
    PH_BARRIER();

    const int niter = nkt >> 1;
    for (int it = 0; it < niter; ++it) {
        const int t0 = it * 2, t1 = t0 + 1;
        const bool lastIt = (it == niter - 1);

        // ================= group A: tile t0 in buf 0 =================
        // ph1: read B+Aq0(buf0); stage T(t1).A0+A1 -> buf1
        READ_Q0(0);
        STAGE_G(t1, 0, 0); STAGE_G(t1, 0, 1);
        PH_BARRIER();
        MFMA_Q(0);
        PH_BARRIER();
        // ph2: read Aq1(buf0); stage T(t0+2).B0 -> buf0
        READ_QA(0, 1);
        STAGE_G(t0 + 2, 1, 0);
        PH_BARRIER();
        MFMA_Q(1);
        PH_BARRIER();
        // ph3: read Aq2(buf0); stage T(t0+2).B1 -> buf0
        READ_QA(0, 2);
        STAGE_G(t0 + 2, 1, 1);
        PH_BARRIER();
        MFMA_Q(2);
        PH_BARRIER();
        // ph4: read Aq3(buf0); no stage; checkpoint
        READ_QA(0, 3);
        PH_BARRIER();
        MFMA_Q(3);
        if (lastIt) { VMCNT0(); } else { VMCNT4(); }   // lastIt: T(t1).A must drain
        PH_BARRIER();

        // ================= group B: tile t1 in buf 1 =================
        // ph5: read B+Aq0(buf1); stage T(t0+2).A0+A1 -> buf0
        READ_Q0(1);
        STAGE_G(t0 + 2, 0, 0); STAGE_G(t0 + 2, 0, 1);
        PH_BARRIER();
        MFMA_Q(0);
        PH_BARRIER();
        // ph6: read Aq1(buf1); stage T(t1+2).B0 -> buf1
        READ_QA(1, 1);
        STAGE_G(t1 + 2, 1, 0);
        PH_BARRIER();
        MFMA_Q(1);
        PH_BARRIER();
        // ph7: read Aq2(buf1); stage T(t1+2).B1 -> buf1
        READ_QA(1, 2);
        STAGE_G(t1 + 2, 1, 1);
        PH_BARRIER();
        MFMA_Q(2);
        PH_BARRIER();
        // ph8: read Aq3(buf1); no stage; checkpoint
        READ_QA(1, 3);
        PH_BARRIER();
        MFMA_Q(3);
        if (lastIt) { VMCNT0(); } else { VMCNT4(); }
        PH_BARRIER();
    }

    // ---- epilogue: C/D layout col = lane&15, row = (lane>>4)*4 + reg ----
    const int rl = (lane >> 4) * 4;
    const int cl = lane & 15;
    const int row0 = brow + wm * 128;
    const int col0 = bcol + wn * 64;

    if constexpr (EPI == 2) {
        float lsum = 0.f;
#pragma unroll
        for (int m = 0; m < 8; m++)
#pragma unroll
            for (int n = 0; n < 4; n++)
#pragma unroll
                for (int rg = 0; rg < 4; rg++) {
                    int gr = row0 + m * 16 + rl + rg;
                    int gc = col0 + n * 16 + cl;
                    float d = acc[m][n][rg] - aux_f32[(size_t)gr * ldc + gc];
                    lsum += d * d;
                }
#pragma unroll
        for (int msk = 1; msk < 64; msk <<= 1)
            lsum += __shfl_xor(lsum, msk, 64);
        if (lane == 0) atomicAdd(loss_accum, lsum);
        return;
    }

#pragma unroll
    for (int m = 0; m < 8; m++)
#pragma unroll
        for (int n = 0; n < 4; n++)
#pragma unroll
            for (int rg = 0; rg < 4; rg++) {
                int gr = row0 + m * 16 + rl + rg;
                int gc = col0 + n * 16 + cl;
                size_t idxo = (size_t)gr * ldc + gc;
                if constexpr (EPI == 0) {
                    ((unsigned short*)Cptr)[idxo] = f2bf(acc[m][n][rg]);
                } else if constexpr (EPI == 1) {
                    float t = acc[m][n][rg] + aux_f32[gc];
                    ((unsigned short*)Cptr)[idxo] = f2bf(1.f / (1.f + expf(-t)));
                } else {  // EPI == 3
                    float gv = bf2f(aux_bf16[idxo]);
                    ((float*)Cptr)[idxo] = acc[m][n][rg] * gv;
                }
            }
#undef STAGE
#undef STAGE_G
#undef LDA_FRAG
#undef LDB_FRAG
#undef MFMA_Q
#undef READ_Q0
#undef READ_QA
}

// ---------- pmean[n][c] = mean_p prefix[n][p*2048 + c] ----------
__global__ __launch_bounds__(256) void pmean_kernel(
        const unsigned short* __restrict__ prefix, unsigned short* __restrict__ pm) {
    int i  = blockIdx.x * 256 + threadIdx.x;
    int n  = i >> 8;
    int c8 = (i & 255) * 8;
    float acc[8] = {0, 0, 0, 0, 0, 0, 0, 0};
#pragma unroll
    for (int p = 0; p < 8; p++) {
        const unsigned short* src = prefix + (size_t)n * 16384 + p * 2048 + c8;
        uint4 raw = *(const uint4*)src;
        unsigned w[4] = {raw.x, raw.y, raw.z, raw.w};
#pragma unroll
        for (int j = 0; j < 4; j++) {
            float2 fp = bfpair(w[j]);
            acc[2 * j] += fp.x; acc[2 * j + 1] += fp.y;
        }
    }
    uint4 o;
    unsigned* ow = (unsigned*)&o;
#pragma unroll
    for (int j = 0; j < 4; j++)
        ow[j] = (unsigned)f2bf(acc[2 * j] * 0.125f) |
                ((unsigned)f2bf(acc[2 * j + 1] * 0.125f) << 16);
    *(uint4*)(pm + (size_t)n * 2048 + c8) = o;
}

// ---------- attention: one wave per (n,h), P=8 keys, D=128 ----------
__global__ __launch_bounds__(256) void attn_kernel(
        const unsigned short* __restrict__ q, const unsigned short* __restrict__ k,
        const unsigned short* __restrict__ v, unsigned short* __restrict__ o) {
    int gw   = (blockIdx.x * 256 + threadIdx.x) >> 6;
    int lane = threadIdx.x & 63;
    int n = gw >> 4, h = gw & 15;
    size_t qoff = (size_t)n * 2048 + h * 128 + lane * 2;
    float2 qv = bfpair(*(const unsigned*)(q + qoff));
    float s[8];
#pragma unroll
    for (int p = 0; p < 8; p++) {
        size_t koff = (size_t)(n * 8 + p) * 2048 + h * 128 + lane * 2;
        float2 kv = bfpair(*(const unsigned*)(k + koff));
        float d = qv.x * kv.x + qv.y * kv.y;
#pragma unroll
        for (int msk = 1; msk < 64; msk <<= 1) d += __shfl_xor(d, msk, 64);
        s[p] = d * 0.08838834764831845f;
    }
    float mx = s[0];
#pragma unroll
    for (int p = 1; p < 8; p++) mx = fmaxf(mx, s[p]);
    float e[8], den = 0.f;
#pragma unroll
    for (int p = 0; p < 8; p++) { e[p] = expf(s[p] - mx); den += e[p]; }
    float inv = 1.f / den;
    float o0 = 0.f, o1 = 0.f;
#pragma unroll
    for (int p = 0; p < 8; p++) {
        size_t voff = (size_t)(n * 8 + p) * 2048 + h * 128 + lane * 2;
        float2 vv = bfpair(*(const unsigned*)(v + voff));
        float a = e[p] * inv;
        o0 += a * vv.x; o1 += a * vv.y;
    }
    *(unsigned*)(o + qoff) = (unsigned)f2bf(o0) | ((unsigned)f2bf(o1) << 16);
}

__global__ __launch_bounds__(64) void finalize_loss_kernel(
        const float* __restrict__ accum, float* __restrict__ dst) {
    if (threadIdx.x == 0) dst[0] = accum[0] * (1.0f / (4096.0f * 2048.0f));
}

// ---------- launch ----------
extern "C" void kernel_launch(void* const* d_in, const int* in_sizes, int n_in,
                              void* d_out, int out_size, void* d_ws, size_t ws_size,
                              hipStream_t stream) {
    const float* x    = (const float*)d_in[0];
    const float* rwkv = (const float*)d_in[1];
    const float* Wq   = (const float*)d_in[2];
    const float* Wk   = (const float*)d_in[3];
    const float* Wv   = (const float*)d_in[4];
    const float* Wo   = (const float*)d_in[5];
    const float* Wg   = (const float*)d_in[6];
    const float* bg   = (const float*)d_in[7];
    const float* Wb   = (const float*)d_in[8];
    const float* Wr   = (const float*)d_in[9];
    float* out = (float*)d_out;
    char*  ws  = (char*)d_ws;

    unsigned short* xs     = (unsigned short*)(ws + 0ull);
    unsigned short* wbT    = (unsigned short*)(ws + 33554432ull);
    unsigned short* wqT    = (unsigned short*)(ws + 167772160ull);
    unsigned short* wkT    = (unsigned short*)(ws + 176160768ull);
    unsigned short* wvT    = (unsigned short*)(ws + 184549376ull);
    unsigned short* wgT    = (unsigned short*)(ws + 192937984ull);
    unsigned short* wrT    = (unsigned short*)(ws + 201326592ull);
    unsigned short* woT    = (unsigned short*)(ws + 209715200ull);
    unsigned short* prefix = (unsigned short*)(ws + 218103808ull);
    unsigned short* vbuf   = (unsigned short*)(ws + 352321536ull);
    unsigned short* qbuf   = (unsigned short*)(ws + 486539264ull);
    unsigned short* gbuf   = (unsigned short*)(ws + 503316480ull);
    unsigned short* pmean  = (unsigned short*)(ws + 520093696ull);
    unsigned short* attno  = (unsigned short*)(ws + 536870912ull);
    float*          lossA  = (float*)(ws + 553648128ull);
    unsigned short* kbuf   = wbT;   // WbT dead after bridge GEMM

    const int SMEM = 131072;
    hipFuncSetAttribute(reinterpret_cast<const void*>(gemm256<0>),
                        hipFuncAttributeMaxDynamicSharedMemorySize, SMEM);
    hipFuncSetAttribute(reinterpret_cast<const void*>(gemm256<1>),
                        hipFuncAttributeMaxDynamicSharedMemorySize, SMEM);
    hipFuncSetAttribute(reinterpret_cast<const void*>(gemm256<2>),
                        hipFuncAttributeMaxDynamicSharedMemorySize, SMEM);
    hipFuncSetAttribute(reinterpret_cast<const void*>(gemm256<3>),
                        hipFuncAttributeMaxDynamicSharedMemorySize, SMEM);

    hipMemsetAsync(lossA, 0, 16, stream);

    pack_xs_kernel<<<16384, 256, 0, stream>>>(x, rwkv, xs);
    transpose_cast_kernel<<<dim3(512, 128), 256, 0, stream>>>(Wb, wbT, 4096, 16384);
    transpose_cast_kernel<<<dim3(64, 64),  256, 0, stream>>>(Wq, wqT, 2048, 2048);
    transpose_cast_kernel<<<dim3(64, 64),  256, 0, stream>>>(Wk, wkT, 2048, 2048);
    transpose_cast_kernel<<<dim3(64, 64),  256, 0, stream>>>(Wv, wvT, 2048, 2048);
    transpose_cast_kernel<<<dim3(64, 64),  256, 0, stream>>>(Wg, wgT, 2048, 2048);
    transpose_cast_kernel<<<dim3(64, 64),  256, 0, stream>>>(Wr, wrT, 2048, 2048);
    transpose_cast_kernel<<<dim3(64, 64),  256, 0, stream>>>(Wo, woT, 2048, 2048);

    // prefix = xs @ Wb          M=4096 N=16384 K=4096 -> 16x64 tiles
    gemm256<0><<<dim3(1024), 512, SMEM, stream>>>(xs, 4096, wbT, 4096,
        prefix, 16384, 4096, 64, nullptr, nullptr, nullptr);
    // k = prefix @ Wk           M=32768 N=2048 K=2048 -> 128x8 tiles
    gemm256<0><<<dim3(1024), 512, SMEM, stream>>>(prefix, 2048, wkT, 2048,
        kbuf, 2048, 2048, 8, nullptr, nullptr, nullptr);
    // v = prefix @ Wv
    gemm256<0><<<dim3(1024), 512, SMEM, stream>>>(prefix, 2048, wvT, 2048,
        vbuf, 2048, 2048, 8, nullptr, nullptr, nullptr);
    // pmean = mean_p(prefix)
    pmean_kernel<<<4096, 256, 0, stream>>>(prefix, pmean);
    // q = x @ Wq   (x = first 2048 cols of xs, lda=4096)  16x8 tiles
    gemm256<0><<<dim3(128), 512, SMEM, stream>>>(xs, 4096, wqT, 2048,
        qbuf, 2048, 2048, 8, nullptr, nullptr, nullptr);
    // g = sigmoid(x @ Wg + bg)
    gemm256<1><<<dim3(128), 512, SMEM, stream>>>(xs, 4096, wgT, 2048,
        gbuf, 2048, 2048, 8, bg, nullptr, nullptr);
    // recon loss: sum((pmean @ Wr - x)^2)
    gemm256<2><<<dim3(128), 512, SMEM, stream>>>(pmean, 2048, wrT, 2048,
        nullptr, 2048, 2048, 8, x, nullptr, lossA);
    // attention
    attn_kernel<<<16384, 256, 0, stream>>>(qbuf, kbuf, vbuf, attno);
    // out = (attno @ Wo) * g    -> fp32 d_out
    gemm256<3><<<dim3(128), 512, SMEM, stream>>>(attno, 2048, woT, 2048,
        out, 2048, 2048, 8, nullptr, gbuf, nullptr);

    finalize_loss_kernel<<<1, 64, 0, stream>>>(lossA, out + 8388608);
}